// Round 10
// baseline (301.383 us; speedup 1.0000x reference)
//
#include <hip/hip_runtime.h>

// Problem constants (B=1)
#define T_LEN 2048
#define C_DIM 1024
#define H_NUM 16
#define D_DIM 64
#define QKV_N (3 * H_NUM * D_DIM)   // 3072
#define L_CHK 64
#define NC (T_LEN / L_CHK)          // 32

typedef _Float16 h8 __attribute__((ext_vector_type(8)));
typedef _Float16 h4 __attribute__((ext_vector_type(4)));
typedef float f32x4 __attribute__((ext_vector_type(4)));

// ---------------------------------------------------------------------------
// Fused fp32 -> fp16 split, scale 64. x & w_attn get hi+lo; w_proj hi only.
// Block 0 also zeroes the lookback flags (re-poisoned to 0xAA each call).
// ---------------------------------------------------------------------------
__global__ __launch_bounds__(256) void split3_f16(
    const float* __restrict__ x, _Float16* __restrict__ xh,
    _Float16* __restrict__ xl, const float* __restrict__ wa,
    _Float16* __restrict__ wah, _Float16* __restrict__ wal,
    const float* __restrict__ wp, _Float16* __restrict__ wph,
    int* __restrict__ flags) {
  if (blockIdx.x == 0) {
    int t = threadIdx.x;
    __hip_atomic_store(&flags[t], 0, __ATOMIC_RELEASE,
                       __HIP_MEMORY_SCOPE_AGENT);
    __hip_atomic_store(&flags[t + 256], 0, __ATOMIC_RELEASE,
                       __HIP_MEMORY_SCOPE_AGENT);
  }
  int i = (blockIdx.x * 256 + threadIdx.x) * 8;
  const float* src;
  _Float16 *dh, *dl = nullptr;
  int base;
  if (i < 2097152) {
    src = x; dh = xh; dl = xl; base = i;
  } else if (i < 2097152 + 3145728) {
    src = wa; dh = wah; dl = wal; base = i - 2097152;
  } else {
    src = wp; dh = wph; base = i - 5242880;
  }
  float4 a = *(const float4*)(src + base);
  float4 b = *(const float4*)(src + base + 4);
  float v[8] = {a.x, a.y, a.z, a.w, b.x, b.y, b.z, b.w};
  h8 hv, lv;
#pragma unroll
  for (int j = 0; j < 8; ++j) {
    float s = v[j] * 64.f;
    _Float16 h = (_Float16)s;
    hv[j] = h;
    lv[j] = (_Float16)(s - (float)h);
  }
  *(h8*)(dh + base) = hv;
  if (dl) *(h8*)(dl + base) = lv;
}

// ---------------------------------------------------------------------------
// fp16 NT MFMA GEMM, BK=64, XOR-swizzled LDS (16B-block granularity).
// SPLIT3: acc += Ah*Bh + Ah*Bl + Al*Bh (fp32-grade). !SPLIT3: 1 MFMA.
// Tile BM=64 x BN, 256 thr = 2x2 waves of 32 x BN/2.
// ROPE epilogue (BN=128): wave's 64-col span == one q/k/v 64-dim block of
// one head; rotate d<->d+-32 == acc[i][j]<->acc[i][j+-2] (lane-local).
// ---------------------------------------------------------------------------
template <int BN, bool ROPE, bool SPLIT3>
__global__ __launch_bounds__(256) void gemm_nt_f16(
    const _Float16* __restrict__ Ah, const _Float16* __restrict__ Al,
    const _Float16* __restrict__ Bh, const _Float16* __restrict__ Bl,
    float* __restrict__ C, const float* __restrict__ cosb,
    const float* __restrict__ sinb, float* __restrict__ qout,
    float* __restrict__ kout, float* __restrict__ vout, int M, int N, int K,
    float outscale) {
  constexpr int NJ = BN / 32;  // N-tiles per wave
  constexpr int NARR = SPLIT3 ? 2 : 1;
  constexpr int GEMM_BYTES = (64 * 64 * 2 + BN * 64 * 2) * NARR;
  constexpr int ROPE_BYTES = ROPE ? (2 * 64 * 64 * 4) : 0;
  constexpr int SMEM_BYTES = GEMM_BYTES > ROPE_BYTES ? GEMM_BYTES : ROPE_BYTES;
  __shared__ __align__(16) char smem[SMEM_BYTES];
  _Float16* sAh = (_Float16*)smem;
  _Float16* sAl = sAh + 64 * 64;                       // SPLIT3 only
  _Float16* sBh = sAh + 64 * 64 * NARR;
  _Float16* sBl = sBh + BN * 64;                       // SPLIT3 only
  const int tid = threadIdx.x;
  const int wave = tid >> 6;
  const int lane = tid & 63;
  const int bm = blockIdx.y * 64;
  const int bn = blockIdx.x * BN;
  const int wm = wave >> 1;          // 0..1 -> 32-row half
  const int wn = wave & 1;           // 0..1 -> BN/2-col half
  const int srow = lane >> 3;        // 0..7 staging row within chunk
  const int sblk = ((lane & 7) ^ srow) * 8;  // swizzled global block
  const int quad = lane >> 4;        // 0..3
  const int lrow = lane & 15;

  f32x4 acc[2][NJ];
#pragma unroll
  for (int i = 0; i < 2; ++i)
#pragma unroll
    for (int j = 0; j < NJ; ++j) acc[i][j] = (f32x4){0.f, 0.f, 0.f, 0.f};

  for (int k0 = 0; k0 < K; k0 += 64) {
#pragma unroll
    for (int it = 0; it < 2; ++it) {
      const int ch = wave + it * 4;  // 0..7
      const int row = ch * 8 + srow;
      const _Float16* ga = Ah + (size_t)(bm + row) * K + k0 + sblk;
      __builtin_amdgcn_global_load_lds(
          (const __attribute__((address_space(1))) void*)ga,
          (__attribute__((address_space(3))) void*)(sAh + ch * 512), 16, 0, 0);
      if constexpr (SPLIT3) {
        const _Float16* gb = Al + (size_t)(bm + row) * K + k0 + sblk;
        __builtin_amdgcn_global_load_lds(
            (const __attribute__((address_space(1))) void*)gb,
            (__attribute__((address_space(3))) void*)(sAl + ch * 512), 16, 0,
            0);
      }
    }
#pragma unroll
    for (int it = 0; it < BN / 32; ++it) {
      const int ch = wave + it * 4;  // 0..BN/8-1
      const int row = ch * 8 + srow;
      const _Float16* ga = Bh + (size_t)(bn + row) * K + k0 + sblk;
      __builtin_amdgcn_global_load_lds(
          (const __attribute__((address_space(1))) void*)ga,
          (__attribute__((address_space(3))) void*)(sBh + ch * 512), 16, 0, 0);
      if constexpr (SPLIT3) {
        const _Float16* gb = Bl + (size_t)(bn + row) * K + k0 + sblk;
        __builtin_amdgcn_global_load_lds(
            (const __attribute__((address_space(1))) void*)gb,
            (__attribute__((address_space(3))) void*)(sBl + ch * 512), 16, 0,
            0);
      }
    }
    __syncthreads();
#pragma unroll
    for (int kk = 0; kk < 2; ++kk) {
      h8 ah[2], al[2], bh[NJ], bl[NJ];
#pragma unroll
      for (int i = 0; i < 2; ++i) {
        const int row = wm * 32 + i * 16 + lrow;
        const int ra = row * 64 + (((kk * 4 + quad) ^ (row & 7)) * 8);
        ah[i] = *(const h8*)&sAh[ra];
        if constexpr (SPLIT3) al[i] = *(const h8*)&sAl[ra];
      }
#pragma unroll
      for (int j = 0; j < NJ; ++j) {
        const int row = wn * (BN / 2) + j * 16 + lrow;
        const int rb = row * 64 + (((kk * 4 + quad) ^ (row & 7)) * 8);
        bh[j] = *(const h8*)&sBh[rb];
        if constexpr (SPLIT3) bl[j] = *(const h8*)&sBl[rb];
      }
#pragma unroll
      for (int i = 0; i < 2; ++i)
#pragma unroll
        for (int j = 0; j < NJ; ++j) {
          acc[i][j] = __builtin_amdgcn_mfma_f32_16x16x32_f16(
              ah[i], bh[j], acc[i][j], 0, 0, 0);
          if constexpr (SPLIT3) {
            acc[i][j] = __builtin_amdgcn_mfma_f32_16x16x32_f16(
                ah[i], bl[j], acc[i][j], 0, 0, 0);
            acc[i][j] = __builtin_amdgcn_mfma_f32_16x16x32_f16(
                al[i], bh[j], acc[i][j], 0, 0, 0);
          }
        }
    }
    __syncthreads();
  }
  // epilogue: C/D layout col=lane&15, row=quad*4+reg
  if constexpr (!ROPE) {
#pragma unroll
    for (int i = 0; i < 2; ++i) {
      const int rbase = bm + wm * 32 + i * 16 + quad * 4;
#pragma unroll
      for (int j = 0; j < NJ; ++j) {
        const int col = bn + wn * (BN / 2) + j * 16 + lrow;
#pragma unroll
        for (int r = 0; r < 4; ++r)
          C[(size_t)(rbase + r) * N + col] = acc[i][j][r] * outscale;
      }
    }
  } else {
    float* cs = (float*)smem;
    float* sn = cs + 4096;
#pragma unroll
    for (int m = 0; m < 4; ++m) {
      int el = (tid + m * 256) * 4;
      *(float4*)&cs[el] = *(const float4*)&cosb[bm * D_DIM + el];
      *(float4*)&sn[el] = *(const float4*)&sinb[bm * D_DIM + el];
    }
    __syncthreads();
    const int colbase = bn + wn * 64;       // multiple of 64
    const int type = (colbase >> 6) % 3;    // 0=q, 1=k, 2=v
    const int head = colbase / 192;
    float* dst = (type == 0) ? qout : (type == 1) ? kout : vout;
    const size_t hbase = (size_t)head * T_LEN * D_DIM;
#pragma unroll
    for (int i = 0; i < 2; ++i) {
      const int tloc0 = wm * 32 + i * 16 + quad * 4;  // t - bm
#pragma unroll
      for (int r = 0; r < 4; ++r) {
        const int tloc = tloc0 + r;
        float* trow = dst + hbase + (size_t)(bm + tloc) * D_DIM;
#pragma unroll
        for (int j = 0; j < NJ; ++j) {
          const int d = j * 16 + lrow;
          float val = acc[i][j][r] * outscale;
          if (type < 2) {
            float rotv = ((j < 2) ? -acc[i][j + 2][r] : acc[i][j - 2][r]) *
                         outscale;
            val = val * cs[tloc * D_DIM + d] + rotv * sn[tloc * D_DIM + d];
          }
          trow[d] = val;
        }
      }
    }
  }
}

// ---------------------------------------------------------------------------
// Fused attention: per-(h,c) block computes its chunk aggregates (identical
// math/order to the old chunk_kv), publishes them (fence + agent-scope flag),
// computes S, then decoupled-lookback accumulates the exclusive prefix over
// chunks 0..c-1 (ascending -> bit-identical to the old scan), then output.
// Deadlock-safe: 512 blocks, LDS ~48.8 KB -> 3 blocks/CU -> all co-resident.
// ---------------------------------------------------------------------------
__global__ __launch_bounds__(256) void attn_fused(
    const float* __restrict__ q, const float* __restrict__ k,
    const float* __restrict__ v, float* __restrict__ kvchunk,
    float* __restrict__ kschunk, float* __restrict__ vschunk,
    int* __restrict__ flags, _Float16* __restrict__ yh) {
  __shared__ float Ks[L_CHK * D_DIM];     // K rows; later: KV prefix
  __shared__ float Vs[L_CHK * D_DIM];
  __shared__ float Ss[L_CHK][L_CHK + 1];  // stride 65
  __shared__ float sKp[D_DIM];
  __shared__ float sVp[D_DIM];
  const int blk = blockIdx.x;  // h*NC + c
  const int h = blk / NC, c = blk % NC;
  const int tid = threadIdx.x;
  const int r = tid & 63;
  const int g = tid >> 6;  // 0..3
  const size_t off = ((size_t)h * T_LEN + c * L_CHK) * D_DIM;
#pragma unroll
  for (int m = 0; m < 4; ++m) {
    int el = (tid + m * 256) * 4;
    *(float4*)&Ks[el] = *(const float4*)&k[off + el];
    *(float4*)&Vs[el] = *(const float4*)&v[off + el];
  }
  float qv[D_DIM];
#pragma unroll
  for (int i = 0; i < 16; ++i) {
    float4 t4 = *(const float4*)&q[off + r * D_DIM + i * 4];
    qv[i * 4 + 0] = t4.x; qv[i * 4 + 1] = t4.y;
    qv[i * 4 + 2] = t4.z; qv[i * 4 + 3] = t4.w;
  }
  __syncthreads();
  // (A) chunk aggregates: kv[d][e] = sum_t k[t][d]*v[t][e]; ksum; vsum
  {
    float agg[16] = {};
    for (int t = 0; t < L_CHK; ++t) {
      float ve = Vs[t * D_DIM + r];                     // lane-stride-1
#pragma unroll
      for (int m = 0; m < 16; ++m)
        agg[m] += Ks[t * D_DIM + g * 16 + m] * ve;      // wave-uniform bcast
    }
    float* outb = kvchunk + (size_t)blk * (D_DIM * D_DIM);
#pragma unroll
    for (int m = 0; m < 16; ++m) outb[(g * 16 + m) * D_DIM + r] = agg[m];
    if (tid < 64) {
      float s = 0.f;
      for (int t = 0; t < L_CHK; ++t) s += Ks[t * D_DIM + tid];
      kschunk[blk * D_DIM + tid] = s;
    } else if (tid < 128) {
      float s = 0.f;
      for (int t = 0; t < L_CHK; ++t) s += Vs[t * D_DIM + (tid - 64)];
      vschunk[blk * D_DIM + (tid - 64)] = s;
    }
  }
  __threadfence();
  __syncthreads();
  if (tid == 0)
    __hip_atomic_store(&flags[blk], 1, __ATOMIC_RELEASE,
                       __HIP_MEMORY_SCOPE_AGENT);
  // (B) S matrix (hides lookback latency of other producers)
#pragma unroll
  for (int jj = 0; jj < 16; ++jj) {
    int j = g * 16 + jj;
    const float4* krow = (const float4*)&Ks[j * D_DIM];  // wave-broadcast
    float sdot = 0.f;
#pragma unroll
    for (int i = 0; i < 16; ++i) {
      float4 kj = krow[i];
      sdot += qv[i * 4] * kj.x + qv[i * 4 + 1] * kj.y + qv[i * 4 + 2] * kj.z +
              qv[i * 4 + 3] * kj.w;
    }
    Ss[r][j] = (j <= r) ? (sdot + 1.f) : 0.f;
  }
  __syncthreads();  // all Ks/Vs/Ss uses of phases A/B complete
  // (C) decoupled lookback: exclusive prefix, ascending (bit-identical)
  f32x4 pacc[4];
#pragma unroll
  for (int m = 0; m < 4; ++m) pacc[m] = (f32x4){0.f, 0.f, 0.f, 0.f};
  float kp = 0.f, vp = 0.f;
  if (c > 0) {
    if (tid == 0) {
      for (int cc = 0; cc < c; ++cc)
        while (__hip_atomic_load(&flags[h * NC + cc], __ATOMIC_ACQUIRE,
                                 __HIP_MEMORY_SCOPE_AGENT) == 0) {
        }
    }
    __syncthreads();
    for (int cc = 0; cc < c; ++cc) {
      const float* src = kvchunk + (size_t)(h * NC + cc) * (D_DIM * D_DIM);
#pragma unroll
      for (int m = 0; m < 4; ++m) {
        int el = (tid + m * 256) * 4;
        pacc[m] += *(const f32x4*)&src[el];
      }
      if (tid < 64)
        kp += kschunk[(h * NC + cc) * D_DIM + tid];
      else if (tid < 128)
        vp += vschunk[(h * NC + cc) * D_DIM + (tid - 64)];
    }
  }
  // stage prefix into LDS (overwrite Ks; safe after post-B sync)
#pragma unroll
  for (int m = 0; m < 4; ++m) {
    int el = (tid + m * 256) * 4;
    *(f32x4*)&Ks[el] = pacc[m];
  }
  if (tid < 64)
    sKp[tid] = kp;
  else if (tid < 128)
    sVp[tid - 64] = vp;
  __syncthreads();
  // (D) output
  float den = (float)(c * L_CHK);  // rowsum(S) supplies the (r+1)
#pragma unroll
  for (int i = 0; i < 16; ++i) {
    const float4 kk = *(const float4*)&sKp[i * 4];
    den += qv[i * 4] * kk.x + qv[i * 4 + 1] * kk.y + qv[i * 4 + 2] * kk.z +
           qv[i * 4 + 3] * kk.w;
  }
  float4 num[4];
#pragma unroll
  for (int i = 0; i < 4; ++i) num[i] = *(const float4*)&sVp[g * 16 + i * 4];
#pragma unroll
  for (int d = 0; d < D_DIM; ++d) {
    float qd = qv[d];
    const float4* kvrow = (const float4*)&Ks[d * D_DIM + g * 16];
#pragma unroll
    for (int i = 0; i < 4; ++i) {
      float4 k4 = kvrow[i];
      num[i].x += qd * k4.x; num[i].y += qd * k4.y;
      num[i].z += qd * k4.z; num[i].w += qd * k4.w;
    }
  }
  float rs = 0.f;
#pragma unroll 8
  for (int j = 0; j < L_CHK; ++j) {
    float f = Ss[r][j];
    rs += f;
    const float4* vrow = (const float4*)&Vs[j * D_DIM + g * 16];
#pragma unroll
    for (int i = 0; i < 4; ++i) {
      float4 v4 = vrow[i];
      num[i].x += f * v4.x; num[i].y += f * v4.y;
      num[i].z += f * v4.z; num[i].w += f * v4.w;
    }
  }
  den += rs;
  float inv = 1.f / den;
  int t = c * L_CHK + r;
  size_t ybase = (size_t)t * (H_NUM * D_DIM) + h * D_DIM + g * 16;
#pragma unroll
  for (int i = 0; i < 4; ++i) {
    h4 hv;
    hv[0] = (_Float16)(num[i].x * inv);
    hv[1] = (_Float16)(num[i].y * inv);
    hv[2] = (_Float16)(num[i].z * inv);
    hv[3] = (_Float16)(num[i].w * inv);
    *(h4*)&yh[ybase + i * 4] = hv;
  }
}

// ---------------------------------------------------------------------------
extern "C" void kernel_launch(void* const* d_in, const int* in_sizes, int n_in,
                              void* d_out, int out_size, void* d_ws,
                              size_t ws_size, hipStream_t stream) {
  const float* x = (const float*)d_in[0];       // (1,2048,1024)
  const float* w_attn = (const float*)d_in[1];  // (3072,1024)
  const float* w_proj = (const float*)d_in[2];  // (1024,1024)
  const float* cosb = (const float*)d_in[3];    // (2048,64)
  const float* sinb = (const float*)d_in[4];    // (2048,64)
  float* out = (float*)d_out;                   // (2048,1024)

  char* ws = (char*)d_ws;
  // Region A (0..9MB): kvchunk aggregates + ks/vs aggregates + flags
  float* kvchunk = (float*)ws;                       // 8 MB
  float* kschunk = (float*)(ws + 8388608);           // 128 KB
  float* vschunk = (float*)(ws + 8519680);           // 128 KB
  int* flags = (int*)(ws + 8650752);                 // 2 KB
  // Region B (24..48MB): q/k/v fp32
  float* qbuf = (float*)(ws + 25165824);
  float* kbuf = (float*)(ws + 25165824 + 8388608);
  float* vbuf = (float*)(ws + 25165824 + 16777216);
  // Region C (48..56MB): xh/xl (live split->QKV GEMM); then yh.
  _Float16* xh = (_Float16*)(ws + 50331648);
  _Float16* xl = (_Float16*)(ws + 50331648 + 4194304);
  _Float16* yh = (_Float16*)(ws + 50331648);
  // Region D (56..68MB): wah/wal (live split->QKV GEMM).
  _Float16* wah = (_Float16*)(ws + 58720256);
  _Float16* wal = (_Float16*)(ws + 58720256 + 6291456);
  // Region E (68..72MB): wph (live whole call).
  _Float16* wph = (_Float16*)(ws + 71303168);

  // 0) fused splits (scale 64, undone in epilogues); also zeroes flags
  split3_f16<<<3072, 256, 0, stream>>>(x, xh, xl, w_attn, wah, wal, w_proj,
                                       wph, flags);

  // 1) qkv GEMM (f16x3, BK=64, swizzled) + fused RoPE -> q,k,v; 2^-12
  {
    dim3 grid(QKV_N / 128, T_LEN / 64);   // 24 x 32 = 768 blocks
    gemm_nt_f16<128, true, true><<<grid, 256, 0, stream>>>(
        xh, xl, wah, wal, nullptr, cosb, sinb, qbuf, kbuf, vbuf, T_LEN, QKV_N,
        C_DIM, 1.f / 4096.f);
  }
  // 2) fused attention (chunk sums + lookback scan + output) -> yh fp16
  attn_fused<<<H_NUM * NC, 256, 0, stream>>>(qbuf, kbuf, vbuf, kvchunk,
                                             kschunk, vschunk, flags, yh);
  // 3) out = y @ w_proj^T (plain fp16, BK=64, swizzled): 2^-6
  {
    dim3 grid(C_DIM / 64, T_LEN / 64);    // 16 x 32 = 512 blocks
    gemm_nt_f16<64, false, false><<<grid, 256, 0, stream>>>(
        yh, nullptr, wph, nullptr, out, nullptr, nullptr, nullptr, nullptr,
        nullptr, T_LEN, C_DIM, C_DIM, 1.f / 64.f);
  }
}

// Round 11
// 183.911 us; speedup vs baseline: 1.6387x; 1.6387x over previous
//
#include <hip/hip_runtime.h>

// Problem constants (B=1)
#define T_LEN 2048
#define C_DIM 1024
#define H_NUM 16
#define D_DIM 64
#define QKV_N (3 * H_NUM * D_DIM)   // 3072
#define L_CHK 64
#define NC (T_LEN / L_CHK)          // 32

typedef _Float16 h8 __attribute__((ext_vector_type(8)));
typedef _Float16 h4 __attribute__((ext_vector_type(4)));
typedef float f32x4 __attribute__((ext_vector_type(4)));

// ---------------------------------------------------------------------------
// Fused fp32 -> fp16 split, scale 64. x & w_attn get hi+lo; w_proj hi only.
// ---------------------------------------------------------------------------
__global__ __launch_bounds__(256) void split3_f16(
    const float* __restrict__ x, _Float16* __restrict__ xh,
    _Float16* __restrict__ xl, const float* __restrict__ wa,
    _Float16* __restrict__ wah, _Float16* __restrict__ wal,
    const float* __restrict__ wp, _Float16* __restrict__ wph) {
  int i = (blockIdx.x * 256 + threadIdx.x) * 8;
  const float* src;
  _Float16 *dh, *dl = nullptr;
  int base;
  if (i < 2097152) {
    src = x; dh = xh; dl = xl; base = i;
  } else if (i < 2097152 + 3145728) {
    src = wa; dh = wah; dl = wal; base = i - 2097152;
  } else {
    src = wp; dh = wph; base = i - 5242880;
  }
  float4 a = *(const float4*)(src + base);
  float4 b = *(const float4*)(src + base + 4);
  float v[8] = {a.x, a.y, a.z, a.w, b.x, b.y, b.z, b.w};
  h8 hv, lv;
#pragma unroll
  for (int j = 0; j < 8; ++j) {
    float s = v[j] * 64.f;
    _Float16 h = (_Float16)s;
    hv[j] = h;
    lv[j] = (_Float16)(s - (float)h);
  }
  *(h8*)(dh + base) = hv;
  if (dl) *(h8*)(dl + base) = lv;
}

// ---------------------------------------------------------------------------
// fp16 NT MFMA GEMM, BK=64, XOR-swizzled LDS (16B-block granularity).
// SPLIT3: acc += Ah*Bh + Ah*Bl + Al*Bh (fp32-grade). !SPLIT3: 1 MFMA.
// Tile BM=64 x BN, 256 thr = 2x2 waves of 32 x BN/2.
// ROPE epilogue (BN=128): wave's 64-col span == one q/k/v 64-dim block of
// one head; rotate d<->d+-32 == acc[i][j]<->acc[i][j+-2] (lane-local).
// ---------------------------------------------------------------------------
template <int BN, bool ROPE, bool SPLIT3>
__global__ __launch_bounds__(256) void gemm_nt_f16(
    const _Float16* __restrict__ Ah, const _Float16* __restrict__ Al,
    const _Float16* __restrict__ Bh, const _Float16* __restrict__ Bl,
    float* __restrict__ C, const float* __restrict__ cosb,
    const float* __restrict__ sinb, float* __restrict__ qout,
    float* __restrict__ kout, float* __restrict__ vout, int M, int N, int K,
    float outscale) {
  constexpr int NJ = BN / 32;  // N-tiles per wave
  constexpr int NARR = SPLIT3 ? 2 : 1;
  constexpr int GEMM_BYTES = (64 * 64 * 2 + BN * 64 * 2) * NARR;
  constexpr int ROPE_BYTES = ROPE ? (2 * 64 * 64 * 4) : 0;
  constexpr int SMEM_BYTES = GEMM_BYTES > ROPE_BYTES ? GEMM_BYTES : ROPE_BYTES;
  __shared__ __align__(16) char smem[SMEM_BYTES];
  _Float16* sAh = (_Float16*)smem;
  _Float16* sAl = sAh + 64 * 64;                       // SPLIT3 only
  _Float16* sBh = sAh + 64 * 64 * NARR;
  _Float16* sBl = sBh + BN * 64;                       // SPLIT3 only
  const int tid = threadIdx.x;
  const int wave = tid >> 6;
  const int lane = tid & 63;
  const int bm = blockIdx.y * 64;
  const int bn = blockIdx.x * BN;
  const int wm = wave >> 1;          // 0..1 -> 32-row half
  const int wn = wave & 1;           // 0..1 -> BN/2-col half
  const int srow = lane >> 3;        // 0..7 staging row within chunk
  const int sblk = ((lane & 7) ^ srow) * 8;  // swizzled global block
  const int quad = lane >> 4;        // 0..3
  const int lrow = lane & 15;

  f32x4 acc[2][NJ];
#pragma unroll
  for (int i = 0; i < 2; ++i)
#pragma unroll
    for (int j = 0; j < NJ; ++j) acc[i][j] = (f32x4){0.f, 0.f, 0.f, 0.f};

  for (int k0 = 0; k0 < K; k0 += 64) {
#pragma unroll
    for (int it = 0; it < 2; ++it) {
      const int ch = wave + it * 4;  // 0..7
      const int row = ch * 8 + srow;
      const _Float16* ga = Ah + (size_t)(bm + row) * K + k0 + sblk;
      __builtin_amdgcn_global_load_lds(
          (const __attribute__((address_space(1))) void*)ga,
          (__attribute__((address_space(3))) void*)(sAh + ch * 512), 16, 0, 0);
      if constexpr (SPLIT3) {
        const _Float16* gb = Al + (size_t)(bm + row) * K + k0 + sblk;
        __builtin_amdgcn_global_load_lds(
            (const __attribute__((address_space(1))) void*)gb,
            (__attribute__((address_space(3))) void*)(sAl + ch * 512), 16, 0,
            0);
      }
    }
#pragma unroll
    for (int it = 0; it < BN / 32; ++it) {
      const int ch = wave + it * 4;  // 0..BN/8-1
      const int row = ch * 8 + srow;
      const _Float16* ga = Bh + (size_t)(bn + row) * K + k0 + sblk;
      __builtin_amdgcn_global_load_lds(
          (const __attribute__((address_space(1))) void*)ga,
          (__attribute__((address_space(3))) void*)(sBh + ch * 512), 16, 0, 0);
      if constexpr (SPLIT3) {
        const _Float16* gb = Bl + (size_t)(bn + row) * K + k0 + sblk;
        __builtin_amdgcn_global_load_lds(
            (const __attribute__((address_space(1))) void*)gb,
            (__attribute__((address_space(3))) void*)(sBl + ch * 512), 16, 0,
            0);
      }
    }
    __syncthreads();
#pragma unroll
    for (int kk = 0; kk < 2; ++kk) {
      h8 ah[2], al[2], bh[NJ], bl[NJ];
#pragma unroll
      for (int i = 0; i < 2; ++i) {
        const int row = wm * 32 + i * 16 + lrow;
        const int ra = row * 64 + (((kk * 4 + quad) ^ (row & 7)) * 8);
        ah[i] = *(const h8*)&sAh[ra];
        if constexpr (SPLIT3) al[i] = *(const h8*)&sAl[ra];
      }
#pragma unroll
      for (int j = 0; j < NJ; ++j) {
        const int row = wn * (BN / 2) + j * 16 + lrow;
        const int rb = row * 64 + (((kk * 4 + quad) ^ (row & 7)) * 8);
        bh[j] = *(const h8*)&sBh[rb];
        if constexpr (SPLIT3) bl[j] = *(const h8*)&sBl[rb];
      }
#pragma unroll
      for (int i = 0; i < 2; ++i)
#pragma unroll
        for (int j = 0; j < NJ; ++j) {
          acc[i][j] = __builtin_amdgcn_mfma_f32_16x16x32_f16(
              ah[i], bh[j], acc[i][j], 0, 0, 0);
          if constexpr (SPLIT3) {
            acc[i][j] = __builtin_amdgcn_mfma_f32_16x16x32_f16(
                ah[i], bl[j], acc[i][j], 0, 0, 0);
            acc[i][j] = __builtin_amdgcn_mfma_f32_16x16x32_f16(
                al[i], bh[j], acc[i][j], 0, 0, 0);
          }
        }
    }
    __syncthreads();
  }
  // epilogue: C/D layout col=lane&15, row=quad*4+reg
  if constexpr (!ROPE) {
#pragma unroll
    for (int i = 0; i < 2; ++i) {
      const int rbase = bm + wm * 32 + i * 16 + quad * 4;
#pragma unroll
      for (int j = 0; j < NJ; ++j) {
        const int col = bn + wn * (BN / 2) + j * 16 + lrow;
#pragma unroll
        for (int r = 0; r < 4; ++r)
          C[(size_t)(rbase + r) * N + col] = acc[i][j][r] * outscale;
      }
    }
  } else {
    float* cs = (float*)smem;
    float* sn = cs + 4096;
#pragma unroll
    for (int m = 0; m < 4; ++m) {
      int el = (tid + m * 256) * 4;
      *(float4*)&cs[el] = *(const float4*)&cosb[bm * D_DIM + el];
      *(float4*)&sn[el] = *(const float4*)&sinb[bm * D_DIM + el];
    }
    __syncthreads();
    const int colbase = bn + wn * 64;       // multiple of 64
    const int type = (colbase >> 6) % 3;    // 0=q, 1=k, 2=v
    const int head = colbase / 192;
    float* dst = (type == 0) ? qout : (type == 1) ? kout : vout;
    const size_t hbase = (size_t)head * T_LEN * D_DIM;
#pragma unroll
    for (int i = 0; i < 2; ++i) {
      const int tloc0 = wm * 32 + i * 16 + quad * 4;  // t - bm
#pragma unroll
      for (int r = 0; r < 4; ++r) {
        const int tloc = tloc0 + r;
        float* trow = dst + hbase + (size_t)(bm + tloc) * D_DIM;
#pragma unroll
        for (int j = 0; j < NJ; ++j) {
          const int d = j * 16 + lrow;
          float val = acc[i][j][r] * outscale;
          if (type < 2) {
            float rotv = ((j < 2) ? -acc[i][j + 2][r] : acc[i][j - 2][r]) *
                         outscale;
            val = val * cs[tloc * D_DIM + d] + rotv * sn[tloc * D_DIM + d];
          }
          trow[d] = val;
        }
      }
    }
  }
}

// ---------------------------------------------------------------------------
// Per-(head,chunk) sums: kv[d][e], ksum[d], vsum[d]. One block per (h,c).
// ---------------------------------------------------------------------------
__global__ __launch_bounds__(256) void chunk_kv(
    const float* __restrict__ k, const float* __restrict__ v,
    float* __restrict__ kvchunk, float* __restrict__ kschunk,
    float* __restrict__ vschunk) {
  __shared__ float Ks[L_CHK][D_DIM];
  __shared__ float Vs[L_CHK][D_DIM];
  int blk = blockIdx.x;  // h*NC + c
  const size_t off = ((size_t)(blk / NC) * T_LEN + (blk % NC) * L_CHK) * D_DIM;
  int tid = threadIdx.x;
#pragma unroll
  for (int m = 0; m < 4; ++m) {
    int el = (tid + m * 256) * 4;
    *(float4*)&((float*)Ks)[el] = *(const float4*)&k[off + el];
    *(float4*)&((float*)Vs)[el] = *(const float4*)&v[off + el];
  }
  __syncthreads();
  int e = tid & 63;
  int q2 = tid >> 6;  // 0..3
  float acc[16] = {};
  for (int t = 0; t < L_CHK; ++t) {
    float ve = Vs[t][e];
#pragma unroll
    for (int m = 0; m < 16; ++m) acc[m] += Ks[t][q2 * 16 + m] * ve;
  }
  float* outb = kvchunk + (size_t)blk * (D_DIM * D_DIM);
#pragma unroll
  for (int m = 0; m < 16; ++m) outb[(q2 * 16 + m) * D_DIM + e] = acc[m];
  if (tid < 64) {
    float s = 0.f;
    for (int t = 0; t < L_CHK; ++t) s += Ks[t][tid];
    kschunk[(size_t)blk * D_DIM + tid] = s;
  } else if (tid < 128) {
    float s = 0.f;
    for (int t = 0; t < L_CHK; ++t) s += Vs[t][tid - 64];
    vschunk[(size_t)blk * D_DIM + (tid - 64)] = s;
  }
}

// ---------------------------------------------------------------------------
// Per-(head,chunk) output -> yh fp16, (T, H*D) layout. Each block computes
// its own exclusive prefix over kvchunk/kschunk/vschunk chunks 0..c-1 with
// plain cached loads (kernel boundary after chunk_kv = the fence; ascending
// order = bit-identical to the old scan). 256 thr: r=tid&63, g=tid>>6.
// ---------------------------------------------------------------------------
__global__ __launch_bounds__(256) void attn_out(
    const float* __restrict__ q, const float* __restrict__ k,
    const float* __restrict__ v, const float* __restrict__ kvchunk,
    const float* __restrict__ kschunk, const float* __restrict__ vschunk,
    _Float16* __restrict__ yh) {
  __shared__ float Ks[L_CHK * D_DIM];     // phase1: K rows; later: KV prefix
  __shared__ float Vs[L_CHK * D_DIM];
  __shared__ float Ss[L_CHK][L_CHK + 1];  // stride 65: column access free
  __shared__ float sKp[D_DIM];
  __shared__ float sVp[D_DIM];
  const int blk = blockIdx.x;  // h*NC + c
  const int h = blk / NC, c = blk % NC;
  const int tid = threadIdx.x;
  const int r = tid & 63;
  const int g = tid >> 6;  // 0..3
  const size_t off = ((size_t)h * T_LEN + c * L_CHK) * D_DIM;
#pragma unroll
  for (int m = 0; m < 4; ++m) {
    int el = (tid + m * 256) * 4;
    *(float4*)&Ks[el] = *(const float4*)&k[off + el];
    *(float4*)&Vs[el] = *(const float4*)&v[off + el];
  }
  float qv[D_DIM];
#pragma unroll
  for (int i = 0; i < 16; ++i) {
    float4 t4 = *(const float4*)&q[off + r * D_DIM + i * 4];
    qv[i * 4 + 0] = t4.x; qv[i * 4 + 1] = t4.y;
    qv[i * 4 + 2] = t4.z; qv[i * 4 + 3] = t4.w;
  }
  __syncthreads();
  // S matrix
#pragma unroll
  for (int jj = 0; jj < 16; ++jj) {
    int j = g * 16 + jj;
    const float4* krow = (const float4*)&Ks[j * D_DIM];  // wave-broadcast
    float sdot = 0.f;
#pragma unroll
    for (int i = 0; i < 16; ++i) {
      float4 kj = krow[i];
      sdot += qv[i * 4] * kj.x + qv[i * 4 + 1] * kj.y + qv[i * 4 + 2] * kj.z +
              qv[i * 4 + 3] * kj.w;
    }
    Ss[r][j] = (j <= r) ? (sdot + 1.f) : 0.f;
  }
  __syncthreads();  // Ks free after this
  // exclusive prefix over chunks 0..c-1 (ascending, cached loads)
  f32x4 pacc[4];
#pragma unroll
  for (int m = 0; m < 4; ++m) pacc[m] = (f32x4){0.f, 0.f, 0.f, 0.f};
  float kp = 0.f, vp = 0.f;
  for (int cc = 0; cc < c; ++cc) {
    const float* src = kvchunk + (size_t)(h * NC + cc) * (D_DIM * D_DIM);
#pragma unroll
    for (int m = 0; m < 4; ++m) {
      int el = (tid + m * 256) * 4;
      pacc[m] += *(const f32x4*)&src[el];
    }
    if (tid < 64)
      kp += kschunk[(h * NC + cc) * D_DIM + tid];
    else if (tid < 128)
      vp += vschunk[(h * NC + cc) * D_DIM + (tid - 64)];
  }
#pragma unroll
  for (int m = 0; m < 4; ++m) {
    int el = (tid + m * 256) * 4;
    *(f32x4*)&Ks[el] = pacc[m];
  }
  if (tid < 64)
    sKp[tid] = kp;
  else if (tid < 128)
    sVp[tid - 64] = vp;
  __syncthreads();
  // output
  float den = (float)(c * L_CHK);  // rowsum(S) supplies the (r+1)
#pragma unroll
  for (int i = 0; i < 16; ++i) {
    const float4 kk = *(const float4*)&sKp[i * 4];
    den += qv[i * 4] * kk.x + qv[i * 4 + 1] * kk.y + qv[i * 4 + 2] * kk.z +
           qv[i * 4 + 3] * kk.w;
  }
  float4 num[4];
#pragma unroll
  for (int i = 0; i < 4; ++i) num[i] = *(const float4*)&sVp[g * 16 + i * 4];
#pragma unroll
  for (int d = 0; d < D_DIM; ++d) {
    float qd = qv[d];
    const float4* kvrow = (const float4*)&Ks[d * D_DIM + g * 16];
#pragma unroll
    for (int i = 0; i < 4; ++i) {
      float4 k4 = kvrow[i];
      num[i].x += qd * k4.x; num[i].y += qd * k4.y;
      num[i].z += qd * k4.z; num[i].w += qd * k4.w;
    }
  }
  float rs = 0.f;
#pragma unroll 8
  for (int j = 0; j < L_CHK; ++j) {
    float f = Ss[r][j];
    rs += f;
    const float4* vrow = (const float4*)&Vs[j * D_DIM + g * 16];
#pragma unroll
    for (int i = 0; i < 4; ++i) {
      float4 v4 = vrow[i];
      num[i].x += f * v4.x; num[i].y += f * v4.y;
      num[i].z += f * v4.z; num[i].w += f * v4.w;
    }
  }
  den += rs;
  float inv = 1.f / den;
  int t = c * L_CHK + r;
  size_t ybase = (size_t)t * (H_NUM * D_DIM) + h * D_DIM + g * 16;
#pragma unroll
  for (int i = 0; i < 4; ++i) {
    h4 hv;
    hv[0] = (_Float16)(num[i].x * inv);
    hv[1] = (_Float16)(num[i].y * inv);
    hv[2] = (_Float16)(num[i].z * inv);
    hv[3] = (_Float16)(num[i].w * inv);
    *(h4*)&yh[ybase + i * 4] = hv;
  }
}

// ---------------------------------------------------------------------------
extern "C" void kernel_launch(void* const* d_in, const int* in_sizes, int n_in,
                              void* d_out, int out_size, void* d_ws,
                              size_t ws_size, hipStream_t stream) {
  const float* x = (const float*)d_in[0];       // (1,2048,1024)
  const float* w_attn = (const float*)d_in[1];  // (3072,1024)
  const float* w_proj = (const float*)d_in[2];  // (1024,1024)
  const float* cosb = (const float*)d_in[3];    // (2048,64)
  const float* sinb = (const float*)d_in[4];    // (2048,64)
  float* out = (float*)d_out;                   // (2048,1024)

  char* ws = (char*)d_ws;
  // Region A (0..9MB): kvchunk + ks/vs chunk aggregates
  float* kvchunk = (float*)ws;                       // 8 MB
  float* kschunk = (float*)(ws + 8388608);           // 128 KB
  float* vschunk = (float*)(ws + 8519680);           // 128 KB
  // Region B (24..48MB): q/k/v fp32
  float* qbuf = (float*)(ws + 25165824);
  float* kbuf = (float*)(ws + 25165824 + 8388608);
  float* vbuf = (float*)(ws + 25165824 + 16777216);
  // Region C (48..56MB): xh/xl (live split->QKV GEMM); then yh.
  _Float16* xh = (_Float16*)(ws + 50331648);
  _Float16* xl = (_Float16*)(ws + 50331648 + 4194304);
  _Float16* yh = (_Float16*)(ws + 50331648);
  // Region D (56..68MB): wah/wal (live split->QKV GEMM).
  _Float16* wah = (_Float16*)(ws + 58720256);
  _Float16* wal = (_Float16*)(ws + 58720256 + 6291456);
  // Region E (68..72MB): wph (live whole call).
  _Float16* wph = (_Float16*)(ws + 71303168);

  // 0) fused splits (scale 64, undone in epilogues); w_proj hi-only
  split3_f16<<<3072, 256, 0, stream>>>(x, xh, xl, w_attn, wah, wal, w_proj,
                                       wph);

  // 1) qkv GEMM (f16x3, BK=64, swizzled) + fused RoPE -> q,k,v; 2^-12
  {
    dim3 grid(QKV_N / 128, T_LEN / 64);   // 24 x 32 = 768 blocks
    gemm_nt_f16<128, true, true><<<grid, 256, 0, stream>>>(
        xh, xl, wah, wal, nullptr, cosb, sinb, qbuf, kbuf, vbuf, T_LEN, QKV_N,
        C_DIM, 1.f / 4096.f);
  }
  // 2) per-chunk sums
  chunk_kv<<<H_NUM * NC, 256, 0, stream>>>(kbuf, vbuf, kvchunk, kschunk,
                                           vschunk);
  // 3) attention output (self-computed prefix, cached) -> yh fp16
  attn_out<<<H_NUM * NC, 256, 0, stream>>>(qbuf, kbuf, vbuf, kvchunk, kschunk,
                                           vschunk, yh);
  // 4) out = y @ w_proj^T (plain fp16, BK=64, swizzled): 2^-6
  {
    dim3 grid(C_DIM / 64, T_LEN / 64);    // 16 x 32 = 512 blocks
    gemm_nt_f16<64, false, false><<<grid, 256, 0, stream>>>(
        yh, nullptr, wph, nullptr, out, nullptr, nullptr, nullptr, nullptr,
        nullptr, T_LEN, C_DIM, C_DIM, 1.f / 64.f);
  }
}

// Round 13
// 173.877 us; speedup vs baseline: 1.7333x; 1.0577x over previous
//
#include <hip/hip_runtime.h>

// Problem constants (B=1)
#define T_LEN 2048
#define C_DIM 1024
#define H_NUM 16
#define D_DIM 64
#define QKV_N (3 * H_NUM * D_DIM)   // 3072
#define L_CHK 64
#define NC (T_LEN / L_CHK)          // 32

typedef _Float16 h8 __attribute__((ext_vector_type(8)));
typedef _Float16 h4 __attribute__((ext_vector_type(4)));
typedef float f32x4 __attribute__((ext_vector_type(4)));

// ---------------------------------------------------------------------------
// Fused fp32 -> fp16 split, scale 64. x & w_attn get hi+lo; w_proj hi only.
// ---------------------------------------------------------------------------
__global__ __launch_bounds__(256) void split3_f16(
    const float* __restrict__ x, _Float16* __restrict__ xh,
    _Float16* __restrict__ xl, const float* __restrict__ wa,
    _Float16* __restrict__ wah, _Float16* __restrict__ wal,
    const float* __restrict__ wp, _Float16* __restrict__ wph) {
  int i = (blockIdx.x * 256 + threadIdx.x) * 8;
  const float* src;
  _Float16 *dh, *dl = nullptr;
  int base;
  if (i < 2097152) {
    src = x; dh = xh; dl = xl; base = i;
  } else if (i < 2097152 + 3145728) {
    src = wa; dh = wah; dl = wal; base = i - 2097152;
  } else {
    src = wp; dh = wph; base = i - 5242880;
  }
  float4 a = *(const float4*)(src + base);
  float4 b = *(const float4*)(src + base + 4);
  float v[8] = {a.x, a.y, a.z, a.w, b.x, b.y, b.z, b.w};
  h8 hv, lv;
#pragma unroll
  for (int j = 0; j < 8; ++j) {
    float s = v[j] * 64.f;
    _Float16 h = (_Float16)s;
    hv[j] = h;
    lv[j] = (_Float16)(s - (float)h);
  }
  *(h8*)(dh + base) = hv;
  if (dl) *(h8*)(dl + base) = lv;
}

// ---------------------------------------------------------------------------
// fp16 NT MFMA GEMM, BK=64, XOR-swizzled LDS (16B-block granularity).
// SPLIT3: acc += Ah*Bh + Ah*Bl + Al*Bh (fp32-grade). !SPLIT3: 1 MFMA.
// Tile BM=64 x BN, 256 thr = 2x2 waves of 32 x BN/2.
// ROPE epilogue (BN=128): wave's 64-col span == one q/k/v 64-dim block of
// one head; rotate d<->d+-32 == acc[i][j]<->acc[i][j+-2] (lane-local).
// q,k stored fp32 (den-singularity path); v stored fp16 (num path only).
// ---------------------------------------------------------------------------
template <int BN, bool ROPE, bool SPLIT3>
__global__ __launch_bounds__(256) void gemm_nt_f16(
    const _Float16* __restrict__ Ah, const _Float16* __restrict__ Al,
    const _Float16* __restrict__ Bh, const _Float16* __restrict__ Bl,
    float* __restrict__ C, const float* __restrict__ cosb,
    const float* __restrict__ sinb, float* __restrict__ qout,
    float* __restrict__ kout, _Float16* __restrict__ vout, int M, int N,
    int K, float outscale) {
  constexpr int NJ = BN / 32;  // N-tiles per wave
  constexpr int NARR = SPLIT3 ? 2 : 1;
  constexpr int GEMM_BYTES = (64 * 64 * 2 + BN * 64 * 2) * NARR;
  constexpr int ROPE_BYTES = ROPE ? (2 * 64 * 64 * 4) : 0;
  constexpr int SMEM_BYTES = GEMM_BYTES > ROPE_BYTES ? GEMM_BYTES : ROPE_BYTES;
  __shared__ __align__(16) char smem[SMEM_BYTES];
  _Float16* sAh = (_Float16*)smem;
  _Float16* sAl = sAh + 64 * 64;                       // SPLIT3 only
  _Float16* sBh = sAh + 64 * 64 * NARR;
  _Float16* sBl = sBh + BN * 64;                       // SPLIT3 only
  const int tid = threadIdx.x;
  const int wave = tid >> 6;
  const int lane = tid & 63;
  const int bm = blockIdx.y * 64;
  const int bn = blockIdx.x * BN;
  const int wm = wave >> 1;          // 0..1 -> 32-row half
  const int wn = wave & 1;           // 0..1 -> BN/2-col half
  const int srow = lane >> 3;        // 0..7 staging row within chunk
  const int sblk = ((lane & 7) ^ srow) * 8;  // swizzled global block
  const int quad = lane >> 4;        // 0..3
  const int lrow = lane & 15;

  f32x4 acc[2][NJ];
#pragma unroll
  for (int i = 0; i < 2; ++i)
#pragma unroll
    for (int j = 0; j < NJ; ++j) acc[i][j] = (f32x4){0.f, 0.f, 0.f, 0.f};

  for (int k0 = 0; k0 < K; k0 += 64) {
#pragma unroll
    for (int it = 0; it < 2; ++it) {
      const int ch = wave + it * 4;  // 0..7
      const int row = ch * 8 + srow;
      const _Float16* ga = Ah + (size_t)(bm + row) * K + k0 + sblk;
      __builtin_amdgcn_global_load_lds(
          (const __attribute__((address_space(1))) void*)ga,
          (__attribute__((address_space(3))) void*)(sAh + ch * 512), 16, 0, 0);
      if constexpr (SPLIT3) {
        const _Float16* gb = Al + (size_t)(bm + row) * K + k0 + sblk;
        __builtin_amdgcn_global_load_lds(
            (const __attribute__((address_space(1))) void*)gb,
            (__attribute__((address_space(3))) void*)(sAl + ch * 512), 16, 0,
            0);
      }
    }
#pragma unroll
    for (int it = 0; it < BN / 32; ++it) {
      const int ch = wave + it * 4;  // 0..BN/8-1
      const int row = ch * 8 + srow;
      const _Float16* ga = Bh + (size_t)(bn + row) * K + k0 + sblk;
      __builtin_amdgcn_global_load_lds(
          (const __attribute__((address_space(1))) void*)ga,
          (__attribute__((address_space(3))) void*)(sBh + ch * 512), 16, 0, 0);
      if constexpr (SPLIT3) {
        const _Float16* gb = Bl + (size_t)(bn + row) * K + k0 + sblk;
        __builtin_amdgcn_global_load_lds(
            (const __attribute__((address_space(1))) void*)gb,
            (__attribute__((address_space(3))) void*)(sBl + ch * 512), 16, 0,
            0);
      }
    }
    __syncthreads();
#pragma unroll
    for (int kk = 0; kk < 2; ++kk) {
      h8 ah[2], al[2], bh[NJ], bl[NJ];
#pragma unroll
      for (int i = 0; i < 2; ++i) {
        const int row = wm * 32 + i * 16 + lrow;
        const int ra = row * 64 + (((kk * 4 + quad) ^ (row & 7)) * 8);
        ah[i] = *(const h8*)&sAh[ra];
        if constexpr (SPLIT3) al[i] = *(const h8*)&sAl[ra];
      }
#pragma unroll
      for (int j = 0; j < NJ; ++j) {
        const int row = wn * (BN / 2) + j * 16 + lrow;
        const int rb = row * 64 + (((kk * 4 + quad) ^ (row & 7)) * 8);
        bh[j] = *(const h8*)&sBh[rb];
        if constexpr (SPLIT3) bl[j] = *(const h8*)&sBl[rb];
      }
#pragma unroll
      for (int i = 0; i < 2; ++i)
#pragma unroll
        for (int j = 0; j < NJ; ++j) {
          acc[i][j] = __builtin_amdgcn_mfma_f32_16x16x32_f16(
              ah[i], bh[j], acc[i][j], 0, 0, 0);
          if constexpr (SPLIT3) {
            acc[i][j] = __builtin_amdgcn_mfma_f32_16x16x32_f16(
                ah[i], bl[j], acc[i][j], 0, 0, 0);
            acc[i][j] = __builtin_amdgcn_mfma_f32_16x16x32_f16(
                al[i], bh[j], acc[i][j], 0, 0, 0);
          }
        }
    }
    __syncthreads();
  }
  // epilogue: C/D layout col=lane&15, row=quad*4+reg
  if constexpr (!ROPE) {
#pragma unroll
    for (int i = 0; i < 2; ++i) {
      const int rbase = bm + wm * 32 + i * 16 + quad * 4;
#pragma unroll
      for (int j = 0; j < NJ; ++j) {
        const int col = bn + wn * (BN / 2) + j * 16 + lrow;
#pragma unroll
        for (int r = 0; r < 4; ++r)
          C[(size_t)(rbase + r) * N + col] = acc[i][j][r] * outscale;
      }
    }
  } else {
    float* cs = (float*)smem;
    float* sn = cs + 4096;
#pragma unroll
    for (int m = 0; m < 4; ++m) {
      int el = (tid + m * 256) * 4;
      *(float4*)&cs[el] = *(const float4*)&cosb[bm * D_DIM + el];
      *(float4*)&sn[el] = *(const float4*)&sinb[bm * D_DIM + el];
    }
    __syncthreads();
    const int colbase = bn + wn * 64;       // multiple of 64
    const int type = (colbase >> 6) % 3;    // 0=q, 1=k, 2=v
    const int head = colbase / 192;
    const size_t hbase = (size_t)head * T_LEN * D_DIM;
    if (type == 2) {
      // v: fp16 store (num path)
#pragma unroll
      for (int i = 0; i < 2; ++i) {
        const int tloc0 = wm * 32 + i * 16 + quad * 4;
#pragma unroll
        for (int r = 0; r < 4; ++r) {
          const int tloc = tloc0 + r;
          _Float16* trow = vout + hbase + (size_t)(bm + tloc) * D_DIM;
#pragma unroll
          for (int j = 0; j < NJ; ++j)
            trow[j * 16 + lrow] = (_Float16)(acc[i][j][r] * outscale);
        }
      }
    } else {
      float* dst = (type == 0) ? qout : kout;
#pragma unroll
      for (int i = 0; i < 2; ++i) {
        const int tloc0 = wm * 32 + i * 16 + quad * 4;
#pragma unroll
        for (int r = 0; r < 4; ++r) {
          const int tloc = tloc0 + r;
          float* trow = dst + hbase + (size_t)(bm + tloc) * D_DIM;
#pragma unroll
          for (int j = 0; j < NJ; ++j) {
            const int d = j * 16 + lrow;
            float val = acc[i][j][r] * outscale;
            float rotv =
                ((j < 2) ? -acc[i][j + 2][r] : acc[i][j - 2][r]) * outscale;
            trow[d] =
                val * cs[tloc * D_DIM + d] + rotv * sn[tloc * D_DIM + d];
          }
        }
      }
    }
  }
}

// ---------------------------------------------------------------------------
// Per-(head,chunk) sums: kv[d][e] (fp16 out), ksum[d], vsum[d] (fp32).
// One block per (h,c). v input fp16 -> fp32 LDS.
// ---------------------------------------------------------------------------
__global__ __launch_bounds__(256) void chunk_kv(
    const float* __restrict__ k, const _Float16* __restrict__ v,
    _Float16* __restrict__ kvchunk, float* __restrict__ kschunk,
    float* __restrict__ vschunk) {
  __shared__ float Ks[L_CHK * D_DIM];
  __shared__ float Vs[L_CHK * D_DIM];
  int blk = blockIdx.x;  // h*NC + c
  const size_t off = ((size_t)(blk / NC) * T_LEN + (blk % NC) * L_CHK) * D_DIM;
  int tid = threadIdx.x;
#pragma unroll
  for (int m = 0; m < 4; ++m) {
    int el = (tid + m * 256) * 4;
    *(float4*)&Ks[el] = *(const float4*)&k[off + el];
  }
#pragma unroll
  for (int m = 0; m < 2; ++m) {
    int el = (tid + m * 256) * 8;
    h8 hv8 = *(const h8*)&v[off + el];
#pragma unroll
    for (int j = 0; j < 8; ++j) Vs[el + j] = (float)hv8[j];
  }
  __syncthreads();
  int e = tid & 63;
  int q2 = tid >> 6;  // 0..3
  float acc[16] = {};
  for (int t = 0; t < L_CHK; ++t) {
    float ve = Vs[t * D_DIM + e];
#pragma unroll
    for (int m = 0; m < 16; ++m) acc[m] += Ks[t * D_DIM + q2 * 16 + m] * ve;
  }
  _Float16* outb = kvchunk + (size_t)blk * (D_DIM * D_DIM);
#pragma unroll
  for (int m = 0; m < 16; ++m)
    outb[(q2 * 16 + m) * D_DIM + e] = (_Float16)acc[m];
  if (tid < 64) {
    float s = 0.f;
    for (int t = 0; t < L_CHK; ++t) s += Ks[t * D_DIM + tid];
    kschunk[(size_t)blk * D_DIM + tid] = s;
  } else if (tid < 128) {
    float s = 0.f;
    for (int t = 0; t < L_CHK; ++t) s += Vs[t * D_DIM + (tid - 64)];
    vschunk[(size_t)blk * D_DIM + (tid - 64)] = s;
  }
}

// ---------------------------------------------------------------------------
// Fused exclusive prefix scans over chunks: blocks 0..255 do the D*D state
// (fp16 storage, fp32 accumulation), blocks 256..259 the ks/vs vectors
// (fp32 — kspref feeds the den singularity). Fully unrolled loads.
// ---------------------------------------------------------------------------
__global__ __launch_bounds__(256) void scan_fused(
    const _Float16* __restrict__ kvchunk, _Float16* __restrict__ kvpref,
    const float* __restrict__ kschunk, const float* __restrict__ vschunk,
    float* __restrict__ kspref, float* __restrict__ vspref) {
  int b = blockIdx.x;
  int tid = threadIdx.x;
  if (b < 256) {
    int gid = b * 256 + tid;  // h*4096 + de
    int h = gid >> 12;
    int de = gid & 4095;
    float vals[NC];
#pragma unroll
    for (int c = 0; c < NC; ++c)
      vals[c] = (float)kvchunk[((size_t)(h * NC + c) << 12) + de];
    float run = 0.f;
#pragma unroll
    for (int c = 0; c < NC; ++c) {
      kvpref[((size_t)(h * NC + c) << 12) + de] = (_Float16)run;
      run += vals[c];
    }
  } else {
    int gid = (b - 256) * 256 + tid;  // h*64 + d (total 1024)
    int h = gid >> 6, d = gid & 63;
    float kv_[NC], vv_[NC];
#pragma unroll
    for (int c = 0; c < NC; ++c) {
      size_t idx = (size_t)(h * NC + c) * 64 + d;
      kv_[c] = kschunk[idx];
      vv_[c] = vschunk[idx];
    }
    float rk = 0.f, rv = 0.f;
#pragma unroll
    for (int c = 0; c < NC; ++c) {
      size_t idx = (size_t)(h * NC + c) * 64 + d;
      kspref[idx] = rk;
      vspref[idx] = rv;
      rk += kv_[c];
      rv += vv_[c];
    }
  }
}

// ---------------------------------------------------------------------------
// Per-(head,chunk) output -> yh fp16, (T, H*D) layout.
// 256 threads: r = tid&63 (row), g = tid>>6 (16-dim quarter).
// v and kvpref are fp16 (num path); q/k/kspref fp32 (den path).
// ---------------------------------------------------------------------------
__global__ __launch_bounds__(256) void attn_out(
    const float* __restrict__ q, const float* __restrict__ k,
    const _Float16* __restrict__ v, const _Float16* __restrict__ kvpref,
    const float* __restrict__ kspref, const float* __restrict__ vspref,
    _Float16* __restrict__ yh) {
  __shared__ float Ks[L_CHK * D_DIM];     // phase1: K rows; phase2: KV prefix
  __shared__ float Vs[L_CHK * D_DIM];
  __shared__ float Ss[L_CHK][L_CHK + 1];  // stride 65: column access free
  int blk = blockIdx.x;  // h*NC + c
  int h = blk / NC, c = blk % NC;
  int tid = threadIdx.x;
  int r = tid & 63;
  int g = tid >> 6;  // 0..3
  const size_t off = ((size_t)h * T_LEN + c * L_CHK) * D_DIM;
#pragma unroll
  for (int m = 0; m < 4; ++m) {
    int el = (tid + m * 256) * 4;
    *(float4*)&Ks[el] = *(const float4*)&k[off + el];
  }
#pragma unroll
  for (int m = 0; m < 2; ++m) {
    int el = (tid + m * 256) * 8;
    h8 hv8 = *(const h8*)&v[off + el];
#pragma unroll
    for (int j = 0; j < 8; ++j) Vs[el + j] = (float)hv8[j];
  }
  float qv[D_DIM];
#pragma unroll
  for (int i = 0; i < 16; ++i) {
    float4 t4 = *(const float4*)&q[off + r * D_DIM + i * 4];
    qv[i * 4 + 0] = t4.x; qv[i * 4 + 1] = t4.y;
    qv[i * 4 + 2] = t4.z; qv[i * 4 + 3] = t4.w;
  }
  __syncthreads();
  // S matrix
#pragma unroll
  for (int jj = 0; jj < 16; ++jj) {
    int j = g * 16 + jj;
    const float4* krow = (const float4*)&Ks[j * D_DIM];  // wave-broadcast
    float sdot = 0.f;
#pragma unroll
    for (int i = 0; i < 16; ++i) {
      float4 kj = krow[i];
      sdot += qv[i * 4] * kj.x + qv[i * 4 + 1] * kj.y + qv[i * 4 + 2] * kj.z +
              qv[i * 4 + 3] * kj.w;
    }
    Ss[r][j] = (j <= r) ? (sdot + 1.f) : 0.f;
  }
  __syncthreads();  // Ks free after this
  // stage KV prefix (fp16 -> fp32 LDS)
  const _Float16* kvp = kvpref + (size_t)blk * (D_DIM * D_DIM);
#pragma unroll
  for (int m = 0; m < 2; ++m) {
    int el = (tid + m * 256) * 8;
    h8 p8 = *(const h8*)&kvp[el];
#pragma unroll
    for (int j = 0; j < 8; ++j) Ks[el + j] = (float)p8[j];
  }
  __syncthreads();
  const float* ksp = kspref + (size_t)blk * D_DIM;
  const float* vsp = vspref + (size_t)blk * D_DIM;
  float den = (float)(c * L_CHK);  // rowsum(S) supplies the (r+1)
#pragma unroll
  for (int i = 0; i < 16; ++i) {
    const float4 kk = *(const float4*)&ksp[i * 4];
    den += qv[i * 4] * kk.x + qv[i * 4 + 1] * kk.y + qv[i * 4 + 2] * kk.z +
           qv[i * 4 + 3] * kk.w;
  }
  float4 num[4];
#pragma unroll
  for (int i = 0; i < 4; ++i) num[i] = *(const float4*)&vsp[g * 16 + i * 4];
#pragma unroll
  for (int d = 0; d < D_DIM; ++d) {
    float qd = qv[d];
    const float4* kvrow = (const float4*)&Ks[d * D_DIM + g * 16];
#pragma unroll
    for (int i = 0; i < 4; ++i) {
      float4 k4 = kvrow[i];
      num[i].x += qd * k4.x; num[i].y += qd * k4.y;
      num[i].z += qd * k4.z; num[i].w += qd * k4.w;
    }
  }
  float rs = 0.f;
#pragma unroll 8
  for (int j = 0; j < L_CHK; ++j) {
    float f = Ss[r][j];
    rs += f;
    const float4* vrow = (const float4*)&Vs[j * D_DIM + g * 16];
#pragma unroll
    for (int i = 0; i < 4; ++i) {
      float4 v4 = vrow[i];
      num[i].x += f * v4.x; num[i].y += f * v4.y;
      num[i].z += f * v4.z; num[i].w += f * v4.w;
    }
  }
  den += rs;
  float inv = 1.f / den;
  int t = c * L_CHK + r;
  size_t ybase = (size_t)t * (H_NUM * D_DIM) + h * D_DIM + g * 16;
#pragma unroll
  for (int i = 0; i < 4; ++i) {
    h4 hv;
    hv[0] = (_Float16)(num[i].x * inv);
    hv[1] = (_Float16)(num[i].y * inv);
    hv[2] = (_Float16)(num[i].z * inv);
    hv[3] = (_Float16)(num[i].w * inv);
    *(h4*)&yh[ybase + i * 4] = hv;
  }
}

// ---------------------------------------------------------------------------
extern "C" void kernel_launch(void* const* d_in, const int* in_sizes, int n_in,
                              void* d_out, int out_size, void* d_ws,
                              size_t ws_size, hipStream_t stream) {
  const float* x = (const float*)d_in[0];       // (1,2048,1024)
  const float* w_attn = (const float*)d_in[1];  // (3072,1024)
  const float* w_proj = (const float*)d_in[2];  // (1024,1024)
  const float* cosb = (const float*)d_in[3];    // (2048,64)
  const float* sinb = (const float*)d_in[4];    // (2048,64)
  float* out = (float*)d_out;                   // (2048,1024)

  char* ws = (char*)d_ws;
  // Region A (0..9MB): kvchunk/kvpref fp16 + ks/vs chunk & prefix vectors
  _Float16* kvchunk = (_Float16*)ws;                 // 4 MB
  _Float16* kvpref = (_Float16*)(ws + 4194304);      // 4 MB
  float* kschunk = (float*)(ws + 8388608);           // 128 KB
  float* vschunk = (float*)(ws + 8519680);           // 128 KB
  float* kspref = (float*)(ws + 8650752);            // 128 KB
  float* vspref = (float*)(ws + 8781824);            // 128 KB
  // Region B (24..48MB): q/k fp32, v fp16
  float* qbuf = (float*)(ws + 25165824);
  float* kbuf = (float*)(ws + 25165824 + 8388608);
  _Float16* vbuf = (_Float16*)(ws + 25165824 + 16777216);  // 4 MB
  // Region C (48..56MB): xh/xl (live split->QKV GEMM); then yh.
  _Float16* xh = (_Float16*)(ws + 50331648);
  _Float16* xl = (_Float16*)(ws + 50331648 + 4194304);
  _Float16* yh = (_Float16*)(ws + 50331648);
  // Region D (56..68MB): wah/wal (live split->QKV GEMM).
  _Float16* wah = (_Float16*)(ws + 58720256);
  _Float16* wal = (_Float16*)(ws + 58720256 + 6291456);
  // Region E (68..72MB): wph (live whole call).
  _Float16* wph = (_Float16*)(ws + 71303168);

  // 0) fused splits (scale 64, undone in epilogues); w_proj hi-only
  split3_f16<<<3072, 256, 0, stream>>>(x, xh, xl, w_attn, wah, wal, w_proj,
                                       wph);

  // 1) qkv GEMM (f16x3, BK=64, swizzled) + fused RoPE -> q,k fp32 / v fp16
  {
    dim3 grid(QKV_N / 128, T_LEN / 64);   // 24 x 32 = 768 blocks
    gemm_nt_f16<128, true, true><<<grid, 256, 0, stream>>>(
        xh, xl, wah, wal, nullptr, cosb, sinb, qbuf, kbuf, vbuf, T_LEN, QKV_N,
        C_DIM, 1.f / 4096.f);
  }
  // 2) per-chunk sums (kvchunk fp16)
  chunk_kv<<<H_NUM * NC, 256, 0, stream>>>(kbuf, vbuf, kvchunk, kschunk,
                                           vschunk);
  // 3) fused prefix scans (256 blocks kv + 4 blocks vec)
  scan_fused<<<260, 256, 0, stream>>>(kvchunk, kvpref, kschunk, vschunk,
                                      kspref, vspref);
  // 4) attention output -> yh (T, H*D) fp16
  attn_out<<<H_NUM * NC, 256, 0, stream>>>(qbuf, kbuf, vbuf, kvpref, kspref,
                                           vspref, yh);
  // 5) out = y @ w_proj^T (plain fp16, BK=64, swizzled): 2^-6
  {
    dim3 grid(C_DIM / 64, T_LEN / 64);    // 16 x 32 = 512 blocks
    gemm_nt_f16<64, false, false><<<grid, 256, 0, stream>>>(
        yh, nullptr, wph, nullptr, out, nullptr, nullptr, nullptr, nullptr,
        nullptr, T_LEN, C_DIM, C_DIM, 1.f / 64.f);
  }
}